// Round 6
// baseline (167.593 us; speedup 1.0000x reference)
//
#include <hip/hip_runtime.h>

#define Bb 16
#define Tt 12
#define Nn 1024
#define FIN 32
#define FOUT 64
#define KC 3
#define KJ (KC * Nn)     // 3072 — GEMM K dimension (k,j)
#define NO (Tt * FOUT)   // 768  — GEMM N dimension (t,o)

#define BM 256
#define BN 192
#define BK 64
#define NKT (KJ / BK)    // 48 K-tiles

typedef __attribute__((ext_vector_type(8))) short short8;
typedef __attribute__((ext_vector_type(4))) float f32x4;

__device__ __forceinline__ unsigned short f2bf(float f) {
  union { float f; unsigned u; } v; v.f = f;
  unsigned r = v.u + 0x7FFFu + ((v.u >> 16) & 1u);  // RNE
  return (unsigned short)(r >> 16);
}

__device__ __forceinline__ void BAR() {
  __builtin_amdgcn_sched_barrier(0);
  __builtin_amdgcn_s_barrier();
  __builtin_amdgcn_sched_barrier(0);
}

// ---------------------------------------------------------------------------
// k1: A[b][i][k*N+j] = bf16(cheb[k,i,j] * att[b,i,j])  (UNCHANGED R5)
// ---------------------------------------------------------------------------
__global__ __launch_bounds__(256) void k1_build_A(
    const float* __restrict__ att, const float* __restrict__ cheb,
    unsigned short* __restrict__ Acat) {
  const unsigned idx = blockIdx.x * 256u + threadIdx.x;  // (b, i, j/8)
  const int j = (idx & 127u) << 3;
  const int i = (idx >> 7) & 1023u;
  const int b = idx >> 17;
  const float* ap = att + ((size_t)b * Nn + i) * Nn + j;
  const float4 a0 = *(const float4*)ap;
  const float4 a1 = *(const float4*)(ap + 4);
  const size_t obase = ((size_t)b * Nn + i) * KJ + j;
#pragma unroll
  for (int k = 0; k < KC; ++k) {
    const float* cp = cheb + ((size_t)k * Nn + i) * Nn + j;
    const float4 c0 = *(const float4*)cp;
    const float4 c1 = *(const float4*)(cp + 4);
    short8 o;
    o[0] = (short)f2bf(a0.x * c0.x); o[1] = (short)f2bf(a0.y * c0.y);
    o[2] = (short)f2bf(a0.z * c0.z); o[3] = (short)f2bf(a0.w * c0.w);
    o[4] = (short)f2bf(a1.x * c1.x); o[5] = (short)f2bf(a1.y * c1.y);
    o[6] = (short)f2bf(a1.z * c1.z); o[7] = (short)f2bf(a1.w * c1.w);
    *(short8*)(Acat + obase + (size_t)k * Nn) = o;
  }
}

// ---------------------------------------------------------------------------
// k2: Y[b][t*64+o][k*N+j] via one MFMA per (k, o-tile)  (UNCHANGED R5)
// ---------------------------------------------------------------------------
__global__ __launch_bounds__(256) void k2_build_Y(
    const float* __restrict__ x, const float* __restrict__ theta,
    unsigned short* __restrict__ Yw) {
  __shared__ float th[KC * FIN * FOUT];  // [k][f][o]
  const int tid = threadIdx.x;
  for (int s = tid; s < KC * FIN * FOUT; s += 256) th[s] = theta[s];
  __syncthreads();

  const int l = tid & 63, w = tid >> 6;
  const int ocol = l & 15;
  const int fr0 = (l >> 4) * 8;

  short8 bfrag[KC * 4];
#pragma unroll
  for (int k = 0; k < KC; ++k)
#pragma unroll
    for (int ot = 0; ot < 4; ++ot) {
      short8 bf;
#pragma unroll
      for (int r = 0; r < 8; ++r)
        bf[r] = (short)f2bf(th[(k * FIN + fr0 + r) * FOUT + ot * 16 + ocol]);
      bfrag[k * 4 + ot] = bf;
    }

  const int blk = blockIdx.x;
  const int jq = blk & 3;
  const int bt = blk >> 2;
  const int t = bt % Tt, b = bt / Tt;
  const size_t ybase = (size_t)(b * NO + t * FOUT) * KJ;
  const f32x4 zero = (f32x4){0.f, 0.f, 0.f, 0.f};

#pragma unroll
  for (int m = 0; m < 4; ++m) {
    const int j0 = jq * 256 + (w * 4 + m) * 16;
    const float* xp = x + ((size_t)(b * Tt + t) * Nn + j0 + (l & 15)) * FIN + fr0;
    const float4 v0 = *(const float4*)xp;
    const float4 v1 = *(const float4*)(xp + 4);
    short8 af;
    af[0] = (short)f2bf(v0.x); af[1] = (short)f2bf(v0.y);
    af[2] = (short)f2bf(v0.z); af[3] = (short)f2bf(v0.w);
    af[4] = (short)f2bf(v1.x); af[5] = (short)f2bf(v1.y);
    af[6] = (short)f2bf(v1.z); af[7] = (short)f2bf(v1.w);

    f32x4 c[KC * 4];
#pragma unroll
    for (int ko = 0; ko < KC * 4; ++ko)
      c[ko] = __builtin_amdgcn_mfma_f32_16x16x32_bf16(af, bfrag[ko], zero, 0, 0, 0);
#pragma unroll
    for (int k = 0; k < KC; ++k)
#pragma unroll
      for (int ot = 0; ot < 4; ++ot) {
        const f32x4 cv = c[k * 4 + ot];
        const int o = ot * 16 + ocol;
        const int jrow = j0 + (l >> 4) * 4;
        uint2 pk;
        pk.x = (unsigned)f2bf(cv[0]) | ((unsigned)f2bf(cv[1]) << 16);
        pk.y = (unsigned)f2bf(cv[2]) | ((unsigned)f2bf(cv[3]) << 16);
        *(uint2*)(Yw + ybase + (size_t)o * KJ + k * Nn + jrow) = pk;
      }
  }
}

// ---------------------------------------------------------------------------
// k3: per b: C[i,n] = sum_kj A[i,kj]·Y[n,kj], ReLU, scatter to out[b,t,i,o].
// 256×192 tile, 256 blocks (100% fill), 8 waves as 4M×2N (wave 64×96).
// ONE barrier per K-tile:
//   reads ks0+ks1 (20 b128, dbuf d) | MFMA ks0 (24, ks1-reads drain under) |
//   lgkm0+vmcnt0+BAR  [all waves done reading d; τ+1 resident+visible;
//                      vmcnt(0) is ~free: newest load is 1 tile old] |
//   stage τ+2 → d (7 units) | MFMA ks1 (24, reg-only — overlaps NEXT tile's
//   ds_reads of d^1, no trailing barrier).
// Hazards: stage→d only after BAR at which every wave passed lgkm0 on its
// d-reads; reads of d^1 touch data staged 2 tiles ago, drained at the
// intervening tile's vmcnt(0)+BAR.
// ---------------------------------------------------------------------------
__global__ __launch_bounds__(512, 2) void k3_gemm(
    const unsigned short* __restrict__ A, const unsigned short* __restrict__ Yw,
    float* __restrict__ out) {
  __shared__ __align__(16) unsigned short lds[57344];  // A 2×32KB, B 2×24KB
  const int bid = blockIdx.x;
  const int logical = (bid & 7) * 32 + (bid >> 3);  // 256 blocks, bijective XCD chunking
  const int b  = logical >> 4;
  const int r  = logical & 15;
  const int it = r >> 2;
  const int nt = r & 3;
  const unsigned short* Ap = A  + ((size_t)b * Nn + it * BM) * KJ;
  const unsigned short* Bp = Yw + ((size_t)b * NO + nt * BN) * KJ;
  const int tid = threadIdx.x;
  const int w = tid >> 6, l = tid & 63;
  const int wm = w >> 1, wn = w & 1;     // 4 M-warps × 2 N-warps (wave 64×96)
  const int lrow = l & 15;
  const int c0 = l >> 4;                 // k-chunk base 0..3
  const int sx = lrow & 7;               // swizzle key (row & 7)

  f32x4 acc[4][6];
#pragma unroll
  for (int mi = 0; mi < 4; ++mi)
#pragma unroll
    for (int ni = 0; ni < 6; ++ni)
      acc[mi][ni] = (f32x4){0.f, 0.f, 0.f, 0.f};

  auto STAGEU = [&](int d, int u, int kt) {
    const int flat = w * 64 + l;        // 0..511
    const int row  = flat >> 3;         // 0..63 within unit
    const int csrc = (flat & 7) ^ (row & 7);
    if (u < 4) {
      __builtin_amdgcn_global_load_lds(
          (const __attribute__((address_space(1))) void*)(Ap + (size_t)(u * 64 + row) * KJ + kt * BK + csrc * 8),
          (__attribute__((address_space(3))) void*)(lds + d * 16384 + u * 4096 + w * 512),
          16, 0, 0);
    } else {
      __builtin_amdgcn_global_load_lds(
          (const __attribute__((address_space(1))) void*)(Bp + (size_t)((u - 4) * 64 + row) * KJ + kt * BK + csrc * 8),
          (__attribute__((address_space(3))) void*)(lds + 32768 + d * 12288 + (u - 4) * 4096 + w * 512),
          16, 0, 0);
    }
  };

  auto LDA = [&](int d, int mi, int ks) -> short8 {
    const int row = wm * 64 + mi * 16 + lrow;       // 0..255
    const int ch  = (c0 | (ks << 2)) ^ sx;          // swizzled chunk
    return *(const short8*)&lds[d * 16384 + row * 64 + ch * 8];
  };
  auto LDB = [&](int d, int ni, int ks) -> short8 {
    const int row = wn * 96 + ni * 16 + lrow;       // 0..191
    const int ch  = (c0 | (ks << 2)) ^ sx;
    return *(const short8*)&lds[32768 + d * 12288 + row * 64 + ch * 8];
  };

  // ---- prologue: tile 0 → dbuf0, tile 1 → dbuf1; tile0 resident ----
#pragma unroll
  for (int u = 0; u < 7; ++u) STAGEU(0, u, 0);
#pragma unroll
  for (int u = 0; u < 7; ++u) STAGEU(1, u, 1);
  asm volatile("s_waitcnt vmcnt(7)" ::: "memory");
  BAR();

  for (int tau = 0; tau < NKT; ++tau) {
    const int d = tau & 1;
    const bool dostage = (tau + 2 < NKT);
    short8 a0[4], b0[6], a1[4], b1[6];
#pragma unroll
    for (int mi = 0; mi < 4; ++mi) a0[mi] = LDA(d, mi, 0);
#pragma unroll
    for (int ni = 0; ni < 6; ++ni) b0[ni] = LDB(d, ni, 0);
#pragma unroll
    for (int mi = 0; mi < 4; ++mi) a1[mi] = LDA(d, mi, 1);
#pragma unroll
    for (int ni = 0; ni < 6; ++ni) b1[ni] = LDB(d, ni, 1);
    __builtin_amdgcn_sched_barrier(0);   // all 20 read-issues precede MFMA
    // MFMA ks0 — ks1 reads drain underneath
    __builtin_amdgcn_s_setprio(1);
#pragma unroll
    for (int mi = 0; mi < 4; ++mi)
#pragma unroll
      for (int ni = 0; ni < 6; ++ni)
        acc[mi][ni] = __builtin_amdgcn_mfma_f32_16x16x32_bf16(a0[mi], b0[ni], acc[mi][ni], 0, 0, 0);
    __builtin_amdgcn_s_setprio(0);
    // single sync point: my d-reads done; τ+1 stages drained (issued 1 tile
    // ago — vmcnt(0) is ~free); barrier publishes both facts to all waves.
    asm volatile("s_waitcnt vmcnt(0) lgkmcnt(0)" ::: "memory");
    BAR();
    if (dostage) {
#pragma unroll
      for (int u = 0; u < 7; ++u) STAGEU(d, u, tau + 2);
    }
    __builtin_amdgcn_sched_barrier(0);
    // MFMA ks1 — register-only; overlaps next tile's ds_reads (no barrier)
    __builtin_amdgcn_s_setprio(1);
#pragma unroll
    for (int mi = 0; mi < 4; ++mi)
#pragma unroll
      for (int ni = 0; ni < 6; ++ni)
        acc[mi][ni] = __builtin_amdgcn_mfma_f32_16x16x32_bf16(a1[mi], b1[ni], acc[mi][ni], 0, 0, 0);
    __builtin_amdgcn_s_setprio(0);
  }
  asm volatile("s_waitcnt vmcnt(0)" ::: "memory");  // drain before endpgm

  const int rbase = it * BM + wm * 64;
  const int cbase = nt * BN + wn * 96;
#pragma unroll
  for (int mi = 0; mi < 4; ++mi) {
#pragma unroll
    for (int ni = 0; ni < 6; ++ni) {
      const int col = cbase + ni * 16 + lrow;   // n = t*64 + o
      const int t = col >> 6, o = col & 63;
      const int row0 = rbase + mi * 16 + (c0 << 2);
      float* op = out + ((size_t)(b * Tt + t) * Nn + row0) * FOUT + o;
      f32x4 v = acc[mi][ni];
#pragma unroll
      for (int q = 0; q < 4; ++q)
        op[(size_t)q * FOUT] = fmaxf(v[q], 0.f);
    }
  }
}

// ---------------------------------------------------------------------------
// fallback (ws too small): slow but correct, pure f32
// ---------------------------------------------------------------------------
__global__ __launch_bounds__(128) void k_fallback(
    const float* __restrict__ x, const float* __restrict__ att,
    const float* __restrict__ cheb, const float* __restrict__ theta,
    float* __restrict__ out) {
  const int blk = blockIdx.x;  // (b, t, i)
  const int i = blk & 1023;
  const int bt = blk >> 10;
  const int t = bt % Tt, b = bt / Tt;
  __shared__ float rhs[KC * FIN];
  const int tid = threadIdx.x;
  if (tid < KC * FIN) {
    const int k = tid >> 5, f = tid & 31;
    const float* ar = att + ((size_t)b * Nn + i) * Nn;
    const float* cr = cheb + ((size_t)k * Nn + i) * Nn;
    const float* xr = x + ((size_t)(b * Tt + t) * Nn) * FIN + f;
    float s = 0.f;
    for (int j = 0; j < Nn; ++j) s = fmaf(ar[j] * cr[j], xr[(size_t)j * FIN], s);
    rhs[tid] = s;
  }
  __syncthreads();
  if (tid < FOUT) {
    float a = 0.f;
#pragma unroll
    for (int kf = 0; kf < KC * FIN; ++kf) a = fmaf(rhs[kf], theta[kf * FOUT + tid], a);
    out[((size_t)(b * Tt + t) * Nn + i) * FOUT + tid] = fmaxf(a, 0.f);
  }
}

extern "C" void kernel_launch(void* const* d_in, const int* in_sizes, int n_in,
                              void* d_out, int out_size, void* d_ws, size_t ws_size,
                              hipStream_t stream) {
  const float* x     = (const float*)d_in[0];
  const float* att   = (const float*)d_in[1];
  const float* cheb  = (const float*)d_in[2];
  const float* theta = (const float*)d_in[3];
  float* out = (float*)d_out;

  const size_t needA = (size_t)Bb * Nn * KJ * sizeof(unsigned short);  // 96 MB
  const size_t needY = (size_t)Bb * NO * KJ * sizeof(unsigned short);  // 72 MB
  if (ws_size >= needA + needY) {
    unsigned short* Acat = (unsigned short*)d_ws;
    unsigned short* Yw   = (unsigned short*)((char*)d_ws + needA);
    hipLaunchKernelGGL(k1_build_A, dim3(Bb * Nn * (Nn / 8) / 256), dim3(256), 0, stream,
                       att, cheb, Acat);
    hipLaunchKernelGGL(k2_build_Y, dim3(Bb * Tt * 4), dim3(256), 0, stream,
                       x, theta, Yw);
    hipLaunchKernelGGL(k3_gemm, dim3(Bb * (Nn / BM) * (NO / BN)), dim3(512), 0, stream,
                       Acat, Yw, out);
  } else {
    hipLaunchKernelGGL(k_fallback, dim3(Bb * Tt * Nn), dim3(128), 0, stream,
                       x, att, cheb, theta, out);
  }
}

// Round 7
// 160.200 us; speedup vs baseline: 1.0461x; 1.0461x over previous
//
#include <hip/hip_runtime.h>

#define Bb 16
#define Tt 12
#define Nn 1024
#define FIN 32
#define FOUT 64
#define KC 3
#define KJ (KC * Nn)     // 3072 — GEMM K dimension (k,j)
#define NO (Tt * FOUT)   // 768  — GEMM N dimension (t,o)

#define BM 128
#define BN 192
#define BK 64
#define NKT (KJ / BK)    // 48 K-tiles

typedef __attribute__((ext_vector_type(8))) short short8;
typedef __attribute__((ext_vector_type(4))) float f32x4;

__device__ __forceinline__ unsigned short f2bf(float f) {
  union { float f; unsigned u; } v; v.f = f;
  unsigned r = v.u + 0x7FFFu + ((v.u >> 16) & 1u);  // RNE
  return (unsigned short)(r >> 16);
}

__device__ __forceinline__ void BAR() {
  __builtin_amdgcn_sched_barrier(0);
  __builtin_amdgcn_s_barrier();
  __builtin_amdgcn_sched_barrier(0);
}

// ---------------------------------------------------------------------------
// k1: A[b][i][k*N+j] = bf16(cheb[k,i,j] * att[b,i,j])  (UNCHANGED R5)
// ---------------------------------------------------------------------------
__global__ __launch_bounds__(256) void k1_build_A(
    const float* __restrict__ att, const float* __restrict__ cheb,
    unsigned short* __restrict__ Acat) {
  const unsigned idx = blockIdx.x * 256u + threadIdx.x;  // (b, i, j/8)
  const int j = (idx & 127u) << 3;
  const int i = (idx >> 7) & 1023u;
  const int b = idx >> 17;
  const float* ap = att + ((size_t)b * Nn + i) * Nn + j;
  const float4 a0 = *(const float4*)ap;
  const float4 a1 = *(const float4*)(ap + 4);
  const size_t obase = ((size_t)b * Nn + i) * KJ + j;
#pragma unroll
  for (int k = 0; k < KC; ++k) {
    const float* cp = cheb + ((size_t)k * Nn + i) * Nn + j;
    const float4 c0 = *(const float4*)cp;
    const float4 c1 = *(const float4*)(cp + 4);
    short8 o;
    o[0] = (short)f2bf(a0.x * c0.x); o[1] = (short)f2bf(a0.y * c0.y);
    o[2] = (short)f2bf(a0.z * c0.z); o[3] = (short)f2bf(a0.w * c0.w);
    o[4] = (short)f2bf(a1.x * c1.x); o[5] = (short)f2bf(a1.y * c1.y);
    o[6] = (short)f2bf(a1.z * c1.z); o[7] = (short)f2bf(a1.w * c1.w);
    *(short8*)(Acat + obase + (size_t)k * Nn) = o;
  }
}

// ---------------------------------------------------------------------------
// k2: Y[b][t*64+o][k*N+j] via one MFMA per (k, o-tile)  (UNCHANGED R5)
// ---------------------------------------------------------------------------
__global__ __launch_bounds__(256) void k2_build_Y(
    const float* __restrict__ x, const float* __restrict__ theta,
    unsigned short* __restrict__ Yw) {
  __shared__ float th[KC * FIN * FOUT];  // [k][f][o]
  const int tid = threadIdx.x;
  for (int s = tid; s < KC * FIN * FOUT; s += 256) th[s] = theta[s];
  __syncthreads();

  const int l = tid & 63, w = tid >> 6;
  const int ocol = l & 15;
  const int fr0 = (l >> 4) * 8;

  short8 bfrag[KC * 4];
#pragma unroll
  for (int k = 0; k < KC; ++k)
#pragma unroll
    for (int ot = 0; ot < 4; ++ot) {
      short8 bf;
#pragma unroll
      for (int r = 0; r < 8; ++r)
        bf[r] = (short)f2bf(th[(k * FIN + fr0 + r) * FOUT + ot * 16 + ocol]);
      bfrag[k * 4 + ot] = bf;
    }

  const int blk = blockIdx.x;
  const int jq = blk & 3;
  const int bt = blk >> 2;
  const int t = bt % Tt, b = bt / Tt;
  const size_t ybase = (size_t)(b * NO + t * FOUT) * KJ;
  const f32x4 zero = (f32x4){0.f, 0.f, 0.f, 0.f};

#pragma unroll
  for (int m = 0; m < 4; ++m) {
    const int j0 = jq * 256 + (w * 4 + m) * 16;
    const float* xp = x + ((size_t)(b * Tt + t) * Nn + j0 + (l & 15)) * FIN + fr0;
    const float4 v0 = *(const float4*)xp;
    const float4 v1 = *(const float4*)(xp + 4);
    short8 af;
    af[0] = (short)f2bf(v0.x); af[1] = (short)f2bf(v0.y);
    af[2] = (short)f2bf(v0.z); af[3] = (short)f2bf(v0.w);
    af[4] = (short)f2bf(v1.x); af[5] = (short)f2bf(v1.y);
    af[6] = (short)f2bf(v1.z); af[7] = (short)f2bf(v1.w);

    f32x4 c[KC * 4];
#pragma unroll
    for (int ko = 0; ko < KC * 4; ++ko)
      c[ko] = __builtin_amdgcn_mfma_f32_16x16x32_bf16(af, bfrag[ko], zero, 0, 0, 0);
#pragma unroll
    for (int k = 0; k < KC; ++k)
#pragma unroll
      for (int ot = 0; ot < 4; ++ot) {
        const f32x4 cv = c[k * 4 + ot];
        const int o = ot * 16 + ocol;
        const int jrow = j0 + (l >> 4) * 4;
        uint2 pk;
        pk.x = (unsigned)f2bf(cv[0]) | ((unsigned)f2bf(cv[1]) << 16);
        pk.y = (unsigned)f2bf(cv[2]) | ((unsigned)f2bf(cv[3]) << 16);
        *(uint2*)(Yw + ybase + (size_t)o * KJ + k * Nn + jrow) = pk;
      }
  }
}

// ---------------------------------------------------------------------------
// k3: per b: C[i,n] = sum_kj A[i,kj]·Y[n,kj], ReLU, scatter to out[b,t,i,o].
// R7: TLP-first retile. 128×192 tile, BK=64, double-buffered = 80 KB LDS
// -> 2 blocks/CU co-resident (512 blocks = exactly 2/CU). 8 waves as 2M×4N
// (wave 64×48: 14 ds_read_b128 + 24 MFMA per K-tile). R6's single-barrier
// rotation kept verbatim: cross-BLOCK overlap (m97/m114 mechanism) hides the
// sync stalls that R4-R6 tried to schedule away within one block.
// ---------------------------------------------------------------------------
__global__ __launch_bounds__(512, 2) void k3_gemm(
    const unsigned short* __restrict__ A, const unsigned short* __restrict__ Yw,
    float* __restrict__ out) {
  __shared__ __align__(16) unsigned short lds[40960];  // A 2×16KB, B 2×24KB
  const int bid = blockIdx.x;
  const int logical = (bid & 7) * 64 + (bid >> 3);  // 512 blocks, bijective XCD chunking
  const int b  = logical >> 5;
  const int r  = logical & 31;
  const int it = r >> 2;
  const int nt = r & 3;
  const unsigned short* Ap = A  + ((size_t)b * Nn + it * BM) * KJ;
  const unsigned short* Bp = Yw + ((size_t)b * NO + nt * BN) * KJ;
  const int tid = threadIdx.x;
  const int w = tid >> 6, l = tid & 63;
  const int wm = w >> 2, wn = w & 3;     // 2 M-warps × 4 N-warps (wave 64×48)
  const int lrow = l & 15;
  const int c0 = l >> 4;                 // k-chunk base 0..3
  const int sx = lrow & 7;               // swizzle key (row & 7)

  f32x4 acc[4][3];
#pragma unroll
  for (int mi = 0; mi < 4; ++mi)
#pragma unroll
    for (int ni = 0; ni < 3; ++ni)
      acc[mi][ni] = (f32x4){0.f, 0.f, 0.f, 0.f};

  // Stage K-tile kt -> dbuf d. A: 1024 16B-chunks (2/thread); B: 1536 (3/thread).
  // Linear LDS dest, inverse-swizzled global source (rule #21).
  auto STAGE = [&](int d, int kt) {
    const int flat = w * 64 + l;        // 0..511
#pragma unroll
    for (int g = 0; g < 2; ++g) {
      const int idx = g * 512 + flat;   // 0..1023 = row*8 + cdst
      const int row = idx >> 3;
      const int csrc = (idx & 7) ^ (row & 7);
      __builtin_amdgcn_global_load_lds(
          (const __attribute__((address_space(1))) void*)(Ap + (size_t)row * KJ + kt * BK + csrc * 8),
          (__attribute__((address_space(3))) void*)(lds + d * 8192 + (g * 512 + w * 64) * 8),
          16, 0, 0);
    }
#pragma unroll
    for (int g = 0; g < 3; ++g) {
      const int idx = g * 512 + flat;   // 0..1535
      const int row = idx >> 3;
      const int csrc = (idx & 7) ^ (row & 7);
      __builtin_amdgcn_global_load_lds(
          (const __attribute__((address_space(1))) void*)(Bp + (size_t)row * KJ + kt * BK + csrc * 8),
          (__attribute__((address_space(3))) void*)(lds + 16384 + d * 12288 + (g * 512 + w * 64) * 8),
          16, 0, 0);
    }
  };

  auto LDA = [&](int d, int mi, int ks) -> short8 {
    const int row = wm * 64 + mi * 16 + lrow;       // 0..127
    const int ch  = (c0 | (ks << 2)) ^ sx;          // swizzled chunk
    return *(const short8*)&lds[d * 8192 + row * 64 + ch * 8];
  };
  auto LDB = [&](int d, int ni, int ks) -> short8 {
    const int row = wn * 48 + ni * 16 + lrow;       // 0..191
    const int ch  = (c0 | (ks << 2)) ^ sx;
    return *(const short8*)&lds[16384 + d * 12288 + row * 64 + ch * 8];
  };

  // ---- prologue: tile 0 → dbuf0, tile 1 → dbuf1; tile0 resident ----
  STAGE(0, 0);
  STAGE(1, 1);
  asm volatile("s_waitcnt vmcnt(5)" ::: "memory");
  BAR();

  for (int tau = 0; tau < NKT; ++tau) {
    const int d = tau & 1;
    const bool dostage = (tau + 2 < NKT);
    short8 a0[4], b0[3], a1[4], b1[3];
#pragma unroll
    for (int mi = 0; mi < 4; ++mi) a0[mi] = LDA(d, mi, 0);
#pragma unroll
    for (int ni = 0; ni < 3; ++ni) b0[ni] = LDB(d, ni, 0);
#pragma unroll
    for (int mi = 0; mi < 4; ++mi) a1[mi] = LDA(d, mi, 1);
#pragma unroll
    for (int ni = 0; ni < 3; ++ni) b1[ni] = LDB(d, ni, 1);
    __builtin_amdgcn_sched_barrier(0);   // all 14 read-issues precede MFMA
    // MFMA ks0 — ks1 reads drain underneath
    __builtin_amdgcn_s_setprio(1);
#pragma unroll
    for (int mi = 0; mi < 4; ++mi)
#pragma unroll
      for (int ni = 0; ni < 3; ++ni)
        acc[mi][ni] = __builtin_amdgcn_mfma_f32_16x16x32_bf16(a0[mi], b0[ni], acc[mi][ni], 0, 0, 0);
    __builtin_amdgcn_s_setprio(0);
    // single sync point: my d-reads done; τ+1 stages drained+published.
    asm volatile("s_waitcnt vmcnt(0) lgkmcnt(0)" ::: "memory");
    BAR();
    if (dostage) STAGE(d, tau + 2);
    __builtin_amdgcn_sched_barrier(0);
    // MFMA ks1 — register-only; overlaps next tile's ds_reads (no barrier)
    __builtin_amdgcn_s_setprio(1);
#pragma unroll
    for (int mi = 0; mi < 4; ++mi)
#pragma unroll
      for (int ni = 0; ni < 3; ++ni)
        acc[mi][ni] = __builtin_amdgcn_mfma_f32_16x16x32_bf16(a1[mi], b1[ni], acc[mi][ni], 0, 0, 0);
    __builtin_amdgcn_s_setprio(0);
  }
  asm volatile("s_waitcnt vmcnt(0)" ::: "memory");  // drain before endpgm

  const int rbase = it * BM + wm * 64;
  const int cbase = nt * BN + wn * 48;
#pragma unroll
  for (int mi = 0; mi < 4; ++mi) {
#pragma unroll
    for (int ni = 0; ni < 3; ++ni) {
      const int col = cbase + ni * 16 + lrow;   // n = t*64 + o
      const int t = col >> 6, o = col & 63;
      const int row0 = rbase + mi * 16 + (c0 << 2);
      float* op = out + ((size_t)(b * Tt + t) * Nn + row0) * FOUT + o;
      f32x4 v = acc[mi][ni];
#pragma unroll
      for (int q = 0; q < 4; ++q)
        op[(size_t)q * FOUT] = fmaxf(v[q], 0.f);
    }
  }
}

// ---------------------------------------------------------------------------
// fallback (ws too small): slow but correct, pure f32
// ---------------------------------------------------------------------------
__global__ __launch_bounds__(128) void k_fallback(
    const float* __restrict__ x, const float* __restrict__ att,
    const float* __restrict__ cheb, const float* __restrict__ theta,
    float* __restrict__ out) {
  const int blk = blockIdx.x;  // (b, t, i)
  const int i = blk & 1023;
  const int bt = blk >> 10;
  const int t = bt % Tt, b = bt / Tt;
  __shared__ float rhs[KC * FIN];
  const int tid = threadIdx.x;
  if (tid < KC * FIN) {
    const int k = tid >> 5, f = tid & 31;
    const float* ar = att + ((size_t)b * Nn + i) * Nn;
    const float* cr = cheb + ((size_t)k * Nn + i) * Nn;
    const float* xr = x + ((size_t)(b * Tt + t) * Nn) * FIN + f;
    float s = 0.f;
    for (int j = 0; j < Nn; ++j) s = fmaf(ar[j] * cr[j], xr[(size_t)j * FIN], s);
    rhs[tid] = s;
  }
  __syncthreads();
  if (tid < FOUT) {
    float a = 0.f;
#pragma unroll
    for (int kf = 0; kf < KC * FIN; ++kf) a = fmaf(rhs[kf], theta[kf * FOUT + tid], a);
    out[((size_t)(b * Tt + t) * Nn + i) * FOUT + tid] = fmaxf(a, 0.f);
  }
}

extern "C" void kernel_launch(void* const* d_in, const int* in_sizes, int n_in,
                              void* d_out, int out_size, void* d_ws, size_t ws_size,
                              hipStream_t stream) {
  const float* x     = (const float*)d_in[0];
  const float* att   = (const float*)d_in[1];
  const float* cheb  = (const float*)d_in[2];
  const float* theta = (const float*)d_in[3];
  float* out = (float*)d_out;

  const size_t needA = (size_t)Bb * Nn * KJ * sizeof(unsigned short);  // 96 MB
  const size_t needY = (size_t)Bb * NO * KJ * sizeof(unsigned short);  // 72 MB
  if (ws_size >= needA + needY) {
    unsigned short* Acat = (unsigned short*)d_ws;
    unsigned short* Yw   = (unsigned short*)((char*)d_ws + needA);
    hipLaunchKernelGGL(k1_build_A, dim3(Bb * Nn * (Nn / 8) / 256), dim3(256), 0, stream,
                       att, cheb, Acat);
    hipLaunchKernelGGL(k2_build_Y, dim3(Bb * Tt * 4), dim3(256), 0, stream,
                       x, theta, Yw);
    hipLaunchKernelGGL(k3_gemm, dim3(Bb * (Nn / BM) * (NO / BN)), dim3(512), 0, stream,
                       Acat, Yw, out);
  } else {
    hipLaunchKernelGGL(k_fallback, dim3(Bb * Tt * Nn), dim3(128), 0, stream,
                       x, att, cheb, theta, out);
  }
}

// Round 8
// 115.470 us; speedup vs baseline: 1.4514x; 1.3874x over previous
//
#include <hip/hip_runtime.h>

#define Bb 16
#define Tt 12
#define Nn 1024
#define FIN 32
#define FOUT 64
#define KC 3
#define KJ (KC * Nn)     // 3072 — A row stride
#define TF (Tt * FIN)    // 384  — (t,f) fused dim
#define NO (Tt * FOUT)   // 768

#define BM 128
#define BN 192
#define BK 64
#define NKT (Nn / BK)    // 16 K-tiles (K = j = 1024)

typedef __attribute__((ext_vector_type(8))) short short8;
typedef __attribute__((ext_vector_type(4))) float f32x4;

__device__ __forceinline__ unsigned short f2bf(float f) {
  union { float f; unsigned u; } v; v.f = f;
  unsigned r = v.u + 0x7FFFu + ((v.u >> 16) & 1u);  // RNE
  return (unsigned short)(r >> 16);
}

__device__ __forceinline__ void BAR() {
  __builtin_amdgcn_sched_barrier(0);
  __builtin_amdgcn_s_barrier();
  __builtin_amdgcn_sched_barrier(0);
}

// ---------------------------------------------------------------------------
// k1: A[b][i][k*N+j] = bf16(cheb[k,i,j] * att[b,i,j])  (UNCHANGED)
// ---------------------------------------------------------------------------
__global__ __launch_bounds__(256) void k1_build_A(
    const float* __restrict__ att, const float* __restrict__ cheb,
    unsigned short* __restrict__ Acat) {
  const unsigned idx = blockIdx.x * 256u + threadIdx.x;  // (b, i, j/8)
  const int j = (idx & 127u) << 3;
  const int i = (idx >> 7) & 1023u;
  const int b = idx >> 17;
  const float* ap = att + ((size_t)b * Nn + i) * Nn + j;
  const float4 a0 = *(const float4*)ap;
  const float4 a1 = *(const float4*)(ap + 4);
  const size_t obase = ((size_t)b * Nn + i) * KJ + j;
#pragma unroll
  for (int k = 0; k < KC; ++k) {
    const float* cp = cheb + ((size_t)k * Nn + i) * Nn + j;
    const float4 c0 = *(const float4*)cp;
    const float4 c1 = *(const float4*)(cp + 4);
    short8 o;
    o[0] = (short)f2bf(a0.x * c0.x); o[1] = (short)f2bf(a0.y * c0.y);
    o[2] = (short)f2bf(a0.z * c0.z); o[3] = (short)f2bf(a0.w * c0.w);
    o[4] = (short)f2bf(a1.x * c1.x); o[5] = (short)f2bf(a1.y * c1.y);
    o[6] = (short)f2bf(a1.z * c1.z); o[7] = (short)f2bf(a1.w * c1.w);
    *(short8*)(Acat + obase + (size_t)k * Nn) = o;
  }
}

// ---------------------------------------------------------------------------
// k2r: YxT[b][t*32+f][j] = bf16(x[b,t,j,f]) — LDS-tiled transpose.
// Block = (b, t, j-chunk of 256). Coalesced reads, coalesced 16B writes.
// ---------------------------------------------------------------------------
__global__ __launch_bounds__(256) void k2r_build_YxT(
    const float* __restrict__ x, unsigned short* __restrict__ YxT) {
  __shared__ float xs[256][33];   // +1 pad
  const int tid = threadIdx.x;
  const int bid = blockIdx.x;     // (b*12 + t)*4 + jc
  const int jc = bid & 3;
  const int bt = bid >> 2;
  const int t = bt % Tt, b = bt / Tt;
  const int j0 = jc * 256;
  const float* xp = x + ((size_t)(b * Tt + t) * Nn + j0) * FIN;
#pragma unroll
  for (int m = 0; m < 8; ++m) {
    const int flat = m * 256 + tid;        // 0..2047 float4s
    const int j_loc = flat >> 3, f4 = flat & 7;
    const float4 v = *(const float4*)(xp + (size_t)j_loc * FIN + f4 * 4);
    xs[j_loc][f4 * 4 + 0] = v.x; xs[j_loc][f4 * 4 + 1] = v.y;
    xs[j_loc][f4 * 4 + 2] = v.z; xs[j_loc][f4 * 4 + 3] = v.w;
  }
  __syncthreads();
  const int f = tid >> 3, jg = tid & 7;    // 32 f-rows × 8 j-groups
  unsigned short* dst = YxT + ((size_t)b * TF + t * FIN + f) * Nn + j0 + jg * 32;
#pragma unroll
  for (int m = 0; m < 4; ++m) {
    short8 sh;
#pragma unroll
    for (int e = 0; e < 8; ++e)
      sh[e] = (short)f2bf(xs[jg * 32 + m * 8 + e][f]);
    *(short8*)(dst + m * 8) = sh;
  }
}

// ---------------------------------------------------------------------------
// k3r: per (b,k): rhs[b][k][i][tf] = sum_j A_k[b][i][j] * YxT[b][tf][j]
// M=1024, N=384, K=1024. R7 pipeline skeleton verbatim (128×192, BK=64,
// 2 blocks/CU, single-barrier dbuf rotation, T2 swizzle). bf16 C-write.
// 768 blocks = 48 (b,k) × 8 it × 2 nt.
// ---------------------------------------------------------------------------
__global__ __launch_bounds__(512, 2) void k3r_gemm(
    const unsigned short* __restrict__ A, const unsigned short* __restrict__ YxT,
    unsigned short* __restrict__ rhs) {
  __shared__ __align__(16) unsigned short lds[40960];  // A 2×16KB, B 2×24KB
  const int bid = blockIdx.x;
  const int logical = (bid & 7) * 96 + (bid >> 3);  // 768 = 8×96, bijective
  const int bk = logical >> 4;          // 0..47 = b*3 + k
  const int r  = logical & 15;
  const int it = r >> 1;                // 0..7
  const int nt = r & 1;                 // 0..1
  const int b  = bk / 3, kk = bk % 3;
  const unsigned short* Ap = A + ((size_t)b * Nn + it * BM) * KJ + (size_t)kk * Nn;
  const unsigned short* Bp = YxT + ((size_t)b * TF + nt * BN) * Nn;
  const int tid = threadIdx.x;
  const int w = tid >> 6, l = tid & 63;
  const int wm = w >> 2, wn = w & 3;     // 2M × 4N (wave 64×48)
  const int lrow = l & 15;
  const int c0 = l >> 4;
  const int sx = lrow & 7;

  f32x4 acc[4][3];
#pragma unroll
  for (int mi = 0; mi < 4; ++mi)
#pragma unroll
    for (int ni = 0; ni < 3; ++ni)
      acc[mi][ni] = (f32x4){0.f, 0.f, 0.f, 0.f};

  auto STAGE = [&](int d, int kt) {
    const int flat = w * 64 + l;        // 0..511
#pragma unroll
    for (int g = 0; g < 2; ++g) {
      const int idx = g * 512 + flat;   // A: 1024 chunks
      const int row = idx >> 3;
      const int csrc = (idx & 7) ^ (row & 7);
      __builtin_amdgcn_global_load_lds(
          (const __attribute__((address_space(1))) void*)(Ap + (size_t)row * KJ + kt * BK + csrc * 8),
          (__attribute__((address_space(3))) void*)(lds + d * 8192 + (g * 512 + w * 64) * 8),
          16, 0, 0);
    }
#pragma unroll
    for (int g = 0; g < 3; ++g) {
      const int idx = g * 512 + flat;   // B: 1536 chunks
      const int row = idx >> 3;
      const int csrc = (idx & 7) ^ (row & 7);
      __builtin_amdgcn_global_load_lds(
          (const __attribute__((address_space(1))) void*)(Bp + (size_t)row * Nn + kt * BK + csrc * 8),
          (__attribute__((address_space(3))) void*)(lds + 16384 + d * 12288 + (g * 512 + w * 64) * 8),
          16, 0, 0);
    }
  };

  auto LDA = [&](int d, int mi, int ks) -> short8 {
    const int row = wm * 64 + mi * 16 + lrow;
    const int ch  = (c0 | (ks << 2)) ^ sx;
    return *(const short8*)&lds[d * 8192 + row * 64 + ch * 8];
  };
  auto LDB = [&](int d, int ni, int ks) -> short8 {
    const int row = wn * 48 + ni * 16 + lrow;
    const int ch  = (c0 | (ks << 2)) ^ sx;
    return *(const short8*)&lds[16384 + d * 12288 + row * 64 + ch * 8];
  };

  STAGE(0, 0);
  STAGE(1, 1);
  asm volatile("s_waitcnt vmcnt(5)" ::: "memory");
  BAR();

  for (int tau = 0; tau < NKT; ++tau) {
    const int d = tau & 1;
    const bool dostage = (tau + 2 < NKT);
    short8 a0[4], b0[3], a1[4], b1[3];
#pragma unroll
    for (int mi = 0; mi < 4; ++mi) a0[mi] = LDA(d, mi, 0);
#pragma unroll
    for (int ni = 0; ni < 3; ++ni) b0[ni] = LDB(d, ni, 0);
#pragma unroll
    for (int mi = 0; mi < 4; ++mi) a1[mi] = LDA(d, mi, 1);
#pragma unroll
    for (int ni = 0; ni < 3; ++ni) b1[ni] = LDB(d, ni, 1);
    __builtin_amdgcn_sched_barrier(0);
    __builtin_amdgcn_s_setprio(1);
#pragma unroll
    for (int mi = 0; mi < 4; ++mi)
#pragma unroll
      for (int ni = 0; ni < 3; ++ni)
        acc[mi][ni] = __builtin_amdgcn_mfma_f32_16x16x32_bf16(a0[mi], b0[ni], acc[mi][ni], 0, 0, 0);
    __builtin_amdgcn_s_setprio(0);
    asm volatile("s_waitcnt vmcnt(0) lgkmcnt(0)" ::: "memory");
    BAR();
    if (dostage) STAGE(d, tau + 2);
    __builtin_amdgcn_sched_barrier(0);
    __builtin_amdgcn_s_setprio(1);
#pragma unroll
    for (int mi = 0; mi < 4; ++mi)
#pragma unroll
      for (int ni = 0; ni < 3; ++ni)
        acc[mi][ni] = __builtin_amdgcn_mfma_f32_16x16x32_bf16(a1[mi], b1[ni], acc[mi][ni], 0, 0, 0);
    __builtin_amdgcn_s_setprio(0);
  }
  asm volatile("s_waitcnt vmcnt(0)" ::: "memory");

  // C-write: rhs[(bk*1024 + it*128 + row)][nt*192 + col] bf16, no ReLU
  unsigned short* Cw = rhs + ((size_t)bk * Nn + it * BM) * TF + nt * BN;
#pragma unroll
  for (int mi = 0; mi < 4; ++mi) {
#pragma unroll
    for (int ni = 0; ni < 3; ++ni) {
      const int col = wn * 48 + ni * 16 + lrow;
      const int row0 = wm * 64 + mi * 16 + c0 * 4;
      unsigned short* op = Cw + (size_t)row0 * TF + col;
      f32x4 v = acc[mi][ni];
#pragma unroll
      for (int q = 0; q < 4; ++q)
        op[(size_t)q * TF] = f2bf(v[q]);
    }
  }
}

// ---------------------------------------------------------------------------
// k4: out[b,t,i,o] = relu( sum_{k,f} rhs[b,k,i,t*32+f] * Theta[k,f,o] )
// Per (b,t): GEMM M=1024(i), N=64(o), K=96(kf). Theta B-frags in registers
// (k2-verified pattern); A-frags read directly from rhs bf16 (one b128 each).
// 768 blocks = (b,t) 192 × 4 i-chunks; 4 waves × 64 i each.
// ---------------------------------------------------------------------------
__global__ __launch_bounds__(256) void k4_epilogue(
    const unsigned short* __restrict__ rhs, const float* __restrict__ theta,
    float* __restrict__ out) {
  __shared__ float th[KC * FIN * FOUT];  // 24 KB, [kf][o]
  const int tid = threadIdx.x;
  for (int s = tid; s < KC * FIN * FOUT; s += 256) th[s] = theta[s];
  __syncthreads();
  const int bid = blockIdx.x;            // (b*12 + t)*4 + ic
  const int ic = bid & 3;
  const int bt = bid >> 2;
  const int t = bt % Tt, b = bt / Tt;
  const int w = tid >> 6, l = tid & 63;
  const int lrow = l & 15;
  const int c0 = l >> 4;
  const int i0 = ic * 256 + w * 64;

  short8 bfrag[KC][4];
#pragma unroll
  for (int ks = 0; ks < KC; ++ks)
#pragma unroll
    for (int oi = 0; oi < 4; ++oi) {
      short8 bf;
#pragma unroll
      for (int rr = 0; rr < 8; ++rr)
        bf[rr] = (short)f2bf(th[(ks * FIN + c0 * 8 + rr) * FOUT + oi * 16 + lrow]);
      bfrag[ks][oi] = bf;
    }

  f32x4 acc[4][4];
#pragma unroll
  for (int mi = 0; mi < 4; ++mi)
#pragma unroll
    for (int oi = 0; oi < 4; ++oi)
      acc[mi][oi] = (f32x4){0.f, 0.f, 0.f, 0.f};

#pragma unroll
  for (int ks = 0; ks < KC; ++ks) {
#pragma unroll
    for (int mi = 0; mi < 4; ++mi) {
      const short8 af = *(const short8*)(
          rhs + ((size_t)(b * KC + ks) * Nn + i0 + mi * 16 + lrow) * TF + t * FIN + c0 * 8);
#pragma unroll
      for (int oi = 0; oi < 4; ++oi)
        acc[mi][oi] = __builtin_amdgcn_mfma_f32_16x16x32_bf16(af, bfrag[ks][oi], acc[mi][oi], 0, 0, 0);
    }
  }

#pragma unroll
  for (int mi = 0; mi < 4; ++mi) {
#pragma unroll
    for (int oi = 0; oi < 4; ++oi) {
      const int row = i0 + mi * 16 + c0 * 4;
      float* op = out + ((size_t)(b * Tt + t) * Nn + row) * FOUT + oi * 16 + lrow;
      f32x4 v = acc[mi][oi];
#pragma unroll
      for (int q = 0; q < 4; ++q)
        op[(size_t)q * FOUT] = fmaxf(v[q], 0.f);
    }
  }
}

// ---------------------------------------------------------------------------
// fallback (ws too small): slow but correct, pure f32
// ---------------------------------------------------------------------------
__global__ __launch_bounds__(128) void k_fallback(
    const float* __restrict__ x, const float* __restrict__ att,
    const float* __restrict__ cheb, const float* __restrict__ theta,
    float* __restrict__ out) {
  const int blk = blockIdx.x;  // (b, t, i)
  const int i = blk & 1023;
  const int bt = blk >> 10;
  const int t = bt % Tt, b = bt / Tt;
  __shared__ float rhs[KC * FIN];
  const int tid = threadIdx.x;
  if (tid < KC * FIN) {
    const int k = tid >> 5, f = tid & 31;
    const float* ar = att + ((size_t)b * Nn + i) * Nn;
    const float* cr = cheb + ((size_t)k * Nn + i) * Nn;
    const float* xr = x + ((size_t)(b * Tt + t) * Nn) * FIN + f;
    float s = 0.f;
    for (int j = 0; j < Nn; ++j) s = fmaf(ar[j] * cr[j], xr[(size_t)j * FIN], s);
    rhs[tid] = s;
  }
  __syncthreads();
  if (tid < FOUT) {
    float a = 0.f;
#pragma unroll
    for (int kf = 0; kf < KC * FIN; ++kf) a = fmaf(rhs[kf], theta[kf * FOUT + tid], a);
    out[((size_t)(b * Tt + t) * Nn + i) * FOUT + tid] = fmaxf(a, 0.f);
  }
}

extern "C" void kernel_launch(void* const* d_in, const int* in_sizes, int n_in,
                              void* d_out, int out_size, void* d_ws, size_t ws_size,
                              hipStream_t stream) {
  const float* x     = (const float*)d_in[0];
  const float* att   = (const float*)d_in[1];
  const float* cheb  = (const float*)d_in[2];
  const float* theta = (const float*)d_in[3];
  float* out = (float*)d_out;

  const size_t needA  = (size_t)Bb * Nn * KJ * sizeof(unsigned short);   // 100.7 MB
  const size_t needYx = (size_t)Bb * TF * Nn * sizeof(unsigned short);   // 12.6 MB
  const size_t needR  = (size_t)Bb * KC * Nn * TF * sizeof(unsigned short); // 37.7 MB
  if (ws_size >= needA + needYx + needR) {
    unsigned short* Acat = (unsigned short*)d_ws;
    unsigned short* YxT  = (unsigned short*)((char*)d_ws + needA);
    unsigned short* rhs  = (unsigned short*)((char*)d_ws + needA + needYx);
    hipLaunchKernelGGL(k1_build_A, dim3(Bb * Nn * (Nn / 8) / 256), dim3(256), 0, stream,
                       att, cheb, Acat);
    hipLaunchKernelGGL(k2r_build_YxT, dim3(Bb * Tt * 4), dim3(256), 0, stream,
                       x, YxT);
    hipLaunchKernelGGL(k3r_gemm, dim3(48 * (Nn / BM) * (TF / BN)), dim3(512), 0, stream,
                       Acat, YxT, rhs);
    hipLaunchKernelGGL(k4_epilogue, dim3(Bb * Tt * 4), dim3(256), 0, stream,
                       rhs, theta, out);
  } else {
    hipLaunchKernelGGL(k_fallback, dim3(Bb * Tt * Nn), dim3(128), 0, stream,
                       x, att, cheb, theta, out);
  }
}

// Round 9
// 106.867 us; speedup vs baseline: 1.5682x; 1.0805x over previous
//
#include <hip/hip_runtime.h>

#define Bb 16
#define Tt 12
#define Nn 1024
#define FIN 32
#define FOUT 64
#define KC 3
#define TF (Tt * FIN)    // 384  — (t,f) fused dim
#define NO (Tt * FOUT)   // 768

#define BM 128
#define BN 192
#define BK 64
#define NKT (Nn / BK)    // 16 K-tiles (K = j = 1024)

typedef __attribute__((ext_vector_type(8))) short short8;
typedef __attribute__((ext_vector_type(4))) float f32x4;

__device__ __forceinline__ unsigned short f2bf(float f) {
  union { float f; unsigned u; } v; v.f = f;
  unsigned r = v.u + 0x7FFFu + ((v.u >> 16) & 1u);  // RNE
  return (unsigned short)(r >> 16);
}

__device__ __forceinline__ void BAR() {
  __builtin_amdgcn_sched_barrier(0);
  __builtin_amdgcn_s_barrier();
  __builtin_amdgcn_sched_barrier(0);
}

// ---------------------------------------------------------------------------
// k2r: YxT[b][t*32+f][j] = bf16(x[b,t,j,f]) — LDS-tiled transpose. (UNCHANGED)
// ---------------------------------------------------------------------------
__global__ __launch_bounds__(256) void k2r_build_YxT(
    const float* __restrict__ x, unsigned short* __restrict__ YxT) {
  __shared__ float xs[256][33];   // +1 pad
  const int tid = threadIdx.x;
  const int bid = blockIdx.x;     // (b*12 + t)*4 + jc
  const int jc = bid & 3;
  const int bt = bid >> 2;
  const int t = bt % Tt, b = bt / Tt;
  const int j0 = jc * 256;
  const float* xp = x + ((size_t)(b * Tt + t) * Nn + j0) * FIN;
#pragma unroll
  for (int m = 0; m < 8; ++m) {
    const int flat = m * 256 + tid;        // 0..2047 float4s
    const int j_loc = flat >> 3, f4 = flat & 7;
    const float4 v = *(const float4*)(xp + (size_t)j_loc * FIN + f4 * 4);
    xs[j_loc][f4 * 4 + 0] = v.x; xs[j_loc][f4 * 4 + 1] = v.y;
    xs[j_loc][f4 * 4 + 2] = v.z; xs[j_loc][f4 * 4 + 3] = v.w;
  }
  __syncthreads();
  const int f = tid >> 3, jg = tid & 7;    // 32 f-rows × 8 j-groups
  unsigned short* dst = YxT + ((size_t)b * TF + t * FIN + f) * Nn + j0 + jg * 32;
#pragma unroll
  for (int m = 0; m < 4; ++m) {
    short8 sh;
#pragma unroll
    for (int e = 0; e < 8; ++e)
      sh[e] = (short)f2bf(xs[jg * 32 + m * 8 + e][f]);
    *(short8*)(dst + m * 8) = sh;
  }
}

// ---------------------------------------------------------------------------
// k3f: FUSED A-build + GEMM. Per (b,k):
//   rhs[b][k][i][tf] = sum_j (cheb[k,i,j]*att[b,i,j])_bf16 * YxT[b][tf][j]
// A-tile is generated on the fly: att/cheb f32 loaded to regs one stage-slot
// ahead (latency covered by a full tile of compute), multiplied, RNE-cvt,
// ds_write_b128 into the swizzled slot (write-side swizzle == read-side
// swizzle involution c^(row&7)). B staged via global_load_lds (inverse-
// swizzled source, linear dest). All frag reads pre-sync => same WAR proof
// as R8. 128×192 tile, BK=64, 80 KB LDS, 2 blocks/CU, 768 blocks.
// ---------------------------------------------------------------------------
__global__ __launch_bounds__(512, 4) void k3f_gemm(
    const float* __restrict__ att, const float* __restrict__ cheb,
    const unsigned short* __restrict__ YxT, unsigned short* __restrict__ rhs) {
  __shared__ __align__(16) unsigned short lds[40960];  // A 2×16KB, B 2×24KB
  const int bid = blockIdx.x;
  const int logical = (bid & 7) * 96 + (bid >> 3);  // 768 = 8×96, bijective
  const int bk = logical >> 4;          // 0..47 = b*3 + k
  const int r  = logical & 15;
  const int it = r >> 1;                // 0..7
  const int nt = r & 1;                 // 0..1
  const int b  = bk / 3, kk = bk % 3;
  const float* Aa = att  + ((size_t)b  * Nn + it * BM) * Nn;   // f32 panel
  const float* Ac = cheb + ((size_t)kk * Nn + it * BM) * Nn;   // f32 panel
  const unsigned short* Bp = YxT + ((size_t)b * TF + nt * BN) * Nn;
  const int tid = threadIdx.x;
  const int w = tid >> 6, l = tid & 63;
  const int wm = w >> 2, wn = w & 3;     // 2M × 4N (wave 64×48)
  const int lrow = l & 15;
  const int c0 = l >> 4;
  const int sx = lrow & 7;

  f32x4 acc[4][3];
#pragma unroll
  for (int mi = 0; mi < 4; ++mi)
#pragma unroll
    for (int ni = 0; ni < 3; ++ni)
      acc[mi][ni] = (f32x4){0.f, 0.f, 0.f, 0.f};

  // in-flight att/cheb regs for one A-tile (2 units × 8 f32 each side)
  float4 ra[4], rc[4];

  auto ISSUE = [&](int kt) {             // issue 8 dwordx4 loads -> ra/rc
#pragma unroll
    for (int u = 0; u < 2; ++u) {
      const int idx = u * 512 + tid;     // 0..1023 = row*8 + c
      const int row = idx >> 3, c = idx & 7;
      const float* ap = Aa + (size_t)row * Nn + kt * BK + c * 8;
      const float* cp = Ac + (size_t)row * Nn + kt * BK + c * 8;
      ra[2 * u]     = *(const float4*)ap;
      ra[2 * u + 1] = *(const float4*)(ap + 4);
      rc[2 * u]     = *(const float4*)cp;
      rc[2 * u + 1] = *(const float4*)(cp + 4);
    }
  };

  auto CVTW = [&](int d) {               // products -> bf16 -> swizzled ds_write
#pragma unroll
    for (int u = 0; u < 2; ++u) {
      const int idx = u * 512 + tid;
      const int row = idx >> 3, c = idx & 7;
      short8 o;
      o[0] = (short)f2bf(ra[2 * u].x * rc[2 * u].x);
      o[1] = (short)f2bf(ra[2 * u].y * rc[2 * u].y);
      o[2] = (short)f2bf(ra[2 * u].z * rc[2 * u].z);
      o[3] = (short)f2bf(ra[2 * u].w * rc[2 * u].w);
      o[4] = (short)f2bf(ra[2 * u + 1].x * rc[2 * u + 1].x);
      o[5] = (short)f2bf(ra[2 * u + 1].y * rc[2 * u + 1].y);
      o[6] = (short)f2bf(ra[2 * u + 1].z * rc[2 * u + 1].z);
      o[7] = (short)f2bf(ra[2 * u + 1].w * rc[2 * u + 1].w);
      *(short8*)&lds[d * 8192 + row * 64 + (c ^ (row & 7)) * 8] = o;
    }
  };

  auto BDMA = [&](int d, int kt) {       // B via global_load_lds (as R8)
#pragma unroll
    for (int g = 0; g < 3; ++g) {
      const int idx = g * 512 + tid;     // 0..1535
      const int row = idx >> 3;
      const int csrc = (idx & 7) ^ (row & 7);
      __builtin_amdgcn_global_load_lds(
          (const __attribute__((address_space(1))) void*)(Bp + (size_t)row * Nn + kt * BK + csrc * 8),
          (__attribute__((address_space(3))) void*)(lds + 16384 + d * 12288 + (g * 512 + w * 64) * 8),
          16, 0, 0);
    }
  };

  auto LDA = [&](int d, int mi, int ks) -> short8 {
    const int row = wm * 64 + mi * 16 + lrow;       // 0..127
    const int ch  = (c0 | (ks << 2)) ^ sx;
    return *(const short8*)&lds[d * 8192 + row * 64 + ch * 8];
  };
  auto LDB = [&](int d, int ni, int ks) -> short8 {
    const int row = wn * 48 + ni * 16 + lrow;       // 0..191
    const int ch  = (c0 | (ks << 2)) ^ sx;
    return *(const short8*)&lds[16384 + d * 12288 + row * 64 + ch * 8];
  };

  // ---- prologue: A(0),A(1) reg-staged+written; B(0),B(1) DMA'd; regs(2) ----
  ISSUE(0);
  asm volatile("s_waitcnt vmcnt(0)" ::: "memory");
  CVTW(0);
  ISSUE(1);
  BDMA(0, 0);
  BDMA(1, 1);
  asm volatile("s_waitcnt vmcnt(6)" ::: "memory");   // ISSUE(1)'s 8 done
  CVTW(1);
  ISSUE(2);
  asm volatile("s_waitcnt vmcnt(0) lgkmcnt(0)" ::: "memory");
  BAR();

  for (int tau = 0; tau < NKT; ++tau) {
    const int d = tau & 1;
    short8 bf[3];
    __builtin_amdgcn_s_setprio(1);
#pragma unroll
    for (int ni = 0; ni < 3; ++ni) bf[ni] = LDB(d, ni, 0);
#pragma unroll
    for (int mi = 0; mi < 4; ++mi) {
      const short8 af = LDA(d, mi, 0);
#pragma unroll
      for (int ni = 0; ni < 3; ++ni)
        acc[mi][ni] = __builtin_amdgcn_mfma_f32_16x16x32_bf16(af, bf[ni], acc[mi][ni], 0, 0, 0);
    }
#pragma unroll
    for (int ni = 0; ni < 3; ++ni) bf[ni] = LDB(d, ni, 1);
#pragma unroll
    for (int mi = 0; mi < 4; ++mi) {
      const short8 af = LDA(d, mi, 1);
#pragma unroll
      for (int ni = 0; ni < 3; ++ni)
        acc[mi][ni] = __builtin_amdgcn_mfma_f32_16x16x32_bf16(af, bf[ni], acc[mi][ni], 0, 0, 0);
    }
    __builtin_amdgcn_s_setprio(0);
    // all dbuf-d reads done (mine: lgkm; all waves: BAR); in-flight regs +
    // B-DMA for this slot drained (vmcnt 0 — newest load is a full tile old)
    asm volatile("s_waitcnt vmcnt(0) lgkmcnt(0)" ::: "memory");
    BAR();
    if (tau + 2 < NKT) { CVTW(d); BDMA(d, tau + 2); }  // stage τ+2 -> dbuf d
    if (tau + 3 < NKT) ISSUE(tau + 3);                 // refill regs
    __builtin_amdgcn_sched_barrier(0);
  }
  asm volatile("s_waitcnt vmcnt(0)" ::: "memory");

  // C-write: rhs[(bk*1024 + it*128 + row)][nt*192 + col] bf16
  unsigned short* Cw = rhs + ((size_t)bk * Nn + it * BM) * TF + nt * BN;
#pragma unroll
  for (int mi = 0; mi < 4; ++mi) {
#pragma unroll
    for (int ni = 0; ni < 3; ++ni) {
      const int col = wn * 48 + ni * 16 + lrow;
      const int row0 = wm * 64 + mi * 16 + c0 * 4;
      unsigned short* op = Cw + (size_t)row0 * TF + col;
      f32x4 v = acc[mi][ni];
#pragma unroll
      for (int q = 0; q < 4; ++q)
        op[(size_t)q * TF] = f2bf(v[q]);
    }
  }
}

// ---------------------------------------------------------------------------
// k4: out[b,t,i,o] = relu( sum_{k,f} rhs[b,k,i,t*32+f] * Theta[k,f,o] )
// (UNCHANGED R8)
// ---------------------------------------------------------------------------
__global__ __launch_bounds__(256) void k4_epilogue(
    const unsigned short* __restrict__ rhs, const float* __restrict__ theta,
    float* __restrict__ out) {
  __shared__ float th[KC * FIN * FOUT];  // 24 KB, [kf][o]
  const int tid = threadIdx.x;
  for (int s = tid; s < KC * FIN * FOUT; s += 256) th[s] = theta[s];
  __syncthreads();
  const int bid = blockIdx.x;            // (b*12 + t)*4 + ic
  const int ic = bid & 3;
  const int bt = bid >> 2;
  const int t = bt % Tt, b = bt / Tt;
  const int w = tid >> 6, l = tid & 63;
  const int lrow = l & 15;
  const int c0 = l >> 4;
  const int i0 = ic * 256 + w * 64;

  short8 bfrag[KC][4];
#pragma unroll
  for (int ks = 0; ks < KC; ++ks)
#pragma unroll
    for (int oi = 0; oi < 4; ++oi) {
      short8 bf;
#pragma unroll
      for (int rr = 0; rr < 8; ++rr)
        bf[rr] = (short)f2bf(th[(ks * FIN + c0 * 8 + rr) * FOUT + oi * 16 + lrow]);
      bfrag[ks][oi] = bf;
    }

  f32x4 acc[4][4];
#pragma unroll
  for (int mi = 0; mi < 4; ++mi)
#pragma unroll
    for (int oi = 0; oi < 4; ++oi)
      acc[mi][oi] = (f32x4){0.f, 0.f, 0.f, 0.f};

#pragma unroll
  for (int ks = 0; ks < KC; ++ks) {
#pragma unroll
    for (int mi = 0; mi < 4; ++mi) {
      const short8 af = *(const short8*)(
          rhs + ((size_t)(b * KC + ks) * Nn + i0 + mi * 16 + lrow) * TF + t * FIN + c0 * 8);
#pragma unroll
      for (int oi = 0; oi < 4; ++oi)
        acc[mi][oi] = __builtin_amdgcn_mfma_f32_16x16x32_bf16(af, bfrag[ks][oi], acc[mi][oi], 0, 0, 0);
    }
  }

#pragma unroll
  for (int mi = 0; mi < 4; ++mi) {
#pragma unroll
    for (int oi = 0; oi < 4; ++oi) {
      const int row = i0 + mi * 16 + c0 * 4;
      float* op = out + ((size_t)(b * Tt + t) * Nn + row) * FOUT + oi * 16 + lrow;
      f32x4 v = acc[mi][oi];
#pragma unroll
      for (int q = 0; q < 4; ++q)
        op[(size_t)q * FOUT] = fmaxf(v[q], 0.f);
    }
  }
}

// ---------------------------------------------------------------------------
// fallback (ws too small): slow but correct, pure f32
// ---------------------------------------------------------------------------
__global__ __launch_bounds__(128) void k_fallback(
    const float* __restrict__ x, const float* __restrict__ att,
    const float* __restrict__ cheb, const float* __restrict__ theta,
    float* __restrict__ out) {
  const int blk = blockIdx.x;  // (b, t, i)
  const int i = blk & 1023;
  const int bt = blk >> 10;
  const int t = bt % Tt, b = bt / Tt;
  __shared__ float rhs[KC * FIN];
  const int tid = threadIdx.x;
  if (tid < KC * FIN) {
    const int k = tid >> 5, f = tid & 31;
    const float* ar = att + ((size_t)b * Nn + i) * Nn;
    const float* cr = cheb + ((size_t)k * Nn + i) * Nn;
    const float* xr = x + ((size_t)(b * Tt + t) * Nn) * FIN + f;
    float s = 0.f;
    for (int j = 0; j < Nn; ++j) s = fmaf(ar[j] * cr[j], xr[(size_t)j * FIN], s);
    rhs[tid] = s;
  }
  __syncthreads();
  if (tid < FOUT) {
    float a = 0.f;
#pragma unroll
    for (int kf = 0; kf < KC * FIN; ++kf) a = fmaf(rhs[kf], theta[kf * FOUT + tid], a);
    out[((size_t)(b * Tt + t) * Nn + i) * FOUT + tid] = fmaxf(a, 0.f);
  }
}

extern "C" void kernel_launch(void* const* d_in, const int* in_sizes, int n_in,
                              void* d_out, int out_size, void* d_ws, size_t ws_size,
                              hipStream_t stream) {
  const float* x     = (const float*)d_in[0];
  const float* att   = (const float*)d_in[1];
  const float* cheb  = (const float*)d_in[2];
  const float* theta = (const float*)d_in[3];
  float* out = (float*)d_out;

  const size_t needYx = (size_t)Bb * TF * Nn * sizeof(unsigned short);      // 12.6 MB
  const size_t needR  = (size_t)Bb * KC * Nn * TF * sizeof(unsigned short); // 37.7 MB
  if (ws_size >= needYx + needR) {
    unsigned short* YxT = (unsigned short*)d_ws;
    unsigned short* rhs = (unsigned short*)((char*)d_ws + needYx);
    hipLaunchKernelGGL(k2r_build_YxT, dim3(Bb * Tt * 4), dim3(256), 0, stream,
                       x, YxT);
    hipLaunchKernelGGL(k3f_gemm, dim3(48 * (Nn / BM) * (TF / BN)), dim3(512), 0, stream,
                       att, cheb, YxT, rhs);
    hipLaunchKernelGGL(k4_epilogue, dim3(Bb * Tt * 4), dim3(256), 0, stream,
                       rhs, theta, out);
  } else {
    hipLaunchKernelGGL(k_fallback, dim3(Bb * Tt * Nn), dim3(128), 0, stream,
                       x, att, cheb, theta, out);
  }
}

// Round 10
// 103.500 us; speedup vs baseline: 1.6193x; 1.0325x over previous
//
#include <hip/hip_runtime.h>

#define Bb 16
#define Tt 12
#define Nn 1024
#define FIN 32
#define FOUT 64
#define KC 3
#define TF (Tt * FIN)    // 384  — (t,f) fused dim
#define NO (Tt * FOUT)   // 768

#define BM 128
#define BN 192
#define BK 64
#define NKT (Nn / BK)    // 16 K-tiles (K = j = 1024)

typedef __attribute__((ext_vector_type(8))) short short8;
typedef __attribute__((ext_vector_type(4))) float f32x4;

__device__ __forceinline__ unsigned short f2bf(float f) {
  union { float f; unsigned u; } v; v.f = f;
  unsigned r = v.u + 0x7FFFu + ((v.u >> 16) & 1u);  // RNE
  return (unsigned short)(r >> 16);
}

__device__ __forceinline__ void BAR() {
  __builtin_amdgcn_sched_barrier(0);
  __builtin_amdgcn_s_barrier();
  __builtin_amdgcn_sched_barrier(0);
}

// ---------------------------------------------------------------------------
// k2r: YxT[b][t*32+f][j] = bf16(x[b,t,j,f]) — LDS-tiled transpose. (UNCHANGED)
// ---------------------------------------------------------------------------
__global__ __launch_bounds__(256) void k2r_build_YxT(
    const float* __restrict__ x, unsigned short* __restrict__ YxT) {
  __shared__ float xs[256][33];   // +1 pad
  const int tid = threadIdx.x;
  const int bid = blockIdx.x;     // (b*12 + t)*4 + jc
  const int jc = bid & 3;
  const int bt = bid >> 2;
  const int t = bt % Tt, b = bt / Tt;
  const int j0 = jc * 256;
  const float* xp = x + ((size_t)(b * Tt + t) * Nn + j0) * FIN;
#pragma unroll
  for (int m = 0; m < 8; ++m) {
    const int flat = m * 256 + tid;        // 0..2047 float4s
    const int j_loc = flat >> 3, f4 = flat & 7;
    const float4 v = *(const float4*)(xp + (size_t)j_loc * FIN + f4 * 4);
    xs[j_loc][f4 * 4 + 0] = v.x; xs[j_loc][f4 * 4 + 1] = v.y;
    xs[j_loc][f4 * 4 + 2] = v.z; xs[j_loc][f4 * 4 + 3] = v.w;
  }
  __syncthreads();
  const int f = tid >> 3, jg = tid & 7;    // 32 f-rows × 8 j-groups
  unsigned short* dst = YxT + ((size_t)b * TF + t * FIN + f) * Nn + j0 + jg * 32;
#pragma unroll
  for (int m = 0; m < 4; ++m) {
    short8 sh;
#pragma unroll
    for (int e = 0; e < 8; ++e)
      sh[e] = (short)f2bf(xs[jg * 32 + m * 8 + e][f]);
    *(short8*)(dst + m * 8) = sh;
  }
}

// ---------------------------------------------------------------------------
// k3f: FUSED A-build + GEMM. Per (b,k):
//   rhs[b][k][i][tf] = sum_j (cheb[k,i,j]*att[b,i,j])_bf16 * YxT[b][tf][j]
// R10: block mapping regrouped so the 6 siblings (3 kk × 2 nt) sharing one
// (b,it) att panel are CONSECUTIVE logicals on the SAME XCD — att panel
// fetched once into that XCD's L2 and hit 5×. Per-tile hot set ~1.3 MB < 4MB
// L2. Everything else identical to R9 (proven correct).
// ---------------------------------------------------------------------------
__global__ __launch_bounds__(512, 4) void k3f_gemm(
    const float* __restrict__ att, const float* __restrict__ cheb,
    const unsigned short* __restrict__ YxT, unsigned short* __restrict__ rhs) {
  __shared__ __align__(16) unsigned short lds[40960];  // A 2×16KB, B 2×24KB
  const int bid = blockIdx.x;
  // 768 blocks. xcd = bid&7 (dispatch round-robin); 96 consecutive logicals
  // per XCD; group g=(b,it) has its 6 members (kk,nt) adjacent.
  const int logical = (bid & 7) * 96 + (bid >> 3);   // bijective
  const int g = logical / 6, m = logical % 6;
  const int b  = g >> 3;
  const int it = g & 7;
  const int kk = m >> 1;
  const int nt = m & 1;
  const int bk = b * 3 + kk;
  const float* Aa = att  + ((size_t)b  * Nn + it * BM) * Nn;   // f32 panel
  const float* Ac = cheb + ((size_t)kk * Nn + it * BM) * Nn;   // f32 panel
  const unsigned short* Bp = YxT + ((size_t)b * TF + nt * BN) * Nn;
  const int tid = threadIdx.x;
  const int w = tid >> 6, l = tid & 63;
  const int wm = w >> 2, wn = w & 3;     // 2M × 4N (wave 64×48)
  const int lrow = l & 15;
  const int c0 = l >> 4;
  const int sx = lrow & 7;

  f32x4 acc[4][3];
#pragma unroll
  for (int mi = 0; mi < 4; ++mi)
#pragma unroll
    for (int ni = 0; ni < 3; ++ni)
      acc[mi][ni] = (f32x4){0.f, 0.f, 0.f, 0.f};

  // in-flight att/cheb regs for one A-tile (2 units × 8 f32 each side)
  float4 ra[4], rc[4];

  auto ISSUE = [&](int kt) {             // issue 8 dwordx4 loads -> ra/rc
#pragma unroll
    for (int u = 0; u < 2; ++u) {
      const int idx = u * 512 + tid;     // 0..1023 = row*8 + c
      const int row = idx >> 3, c = idx & 7;
      const float* ap = Aa + (size_t)row * Nn + kt * BK + c * 8;
      const float* cp = Ac + (size_t)row * Nn + kt * BK + c * 8;
      ra[2 * u]     = *(const float4*)ap;
      ra[2 * u + 1] = *(const float4*)(ap + 4);
      rc[2 * u]     = *(const float4*)cp;
      rc[2 * u + 1] = *(const float4*)(cp + 4);
    }
  };

  auto CVTW = [&](int d) {               // products -> bf16 -> swizzled ds_write
#pragma unroll
    for (int u = 0; u < 2; ++u) {
      const int idx = u * 512 + tid;
      const int row = idx >> 3, c = idx & 7;
      short8 o;
      o[0] = (short)f2bf(ra[2 * u].x * rc[2 * u].x);
      o[1] = (short)f2bf(ra[2 * u].y * rc[2 * u].y);
      o[2] = (short)f2bf(ra[2 * u].z * rc[2 * u].z);
      o[3] = (short)f2bf(ra[2 * u].w * rc[2 * u].w);
      o[4] = (short)f2bf(ra[2 * u + 1].x * rc[2 * u + 1].x);
      o[5] = (short)f2bf(ra[2 * u + 1].y * rc[2 * u + 1].y);
      o[6] = (short)f2bf(ra[2 * u + 1].z * rc[2 * u + 1].z);
      o[7] = (short)f2bf(ra[2 * u + 1].w * rc[2 * u + 1].w);
      *(short8*)&lds[d * 8192 + row * 64 + (c ^ (row & 7)) * 8] = o;
    }
  };

  auto BDMA = [&](int d, int kt) {       // B via global_load_lds
#pragma unroll
    for (int g2 = 0; g2 < 3; ++g2) {
      const int idx = g2 * 512 + tid;    // 0..1535
      const int row = idx >> 3;
      const int csrc = (idx & 7) ^ (row & 7);
      __builtin_amdgcn_global_load_lds(
          (const __attribute__((address_space(1))) void*)(Bp + (size_t)row * Nn + kt * BK + csrc * 8),
          (__attribute__((address_space(3))) void*)(lds + 16384 + d * 12288 + (g2 * 512 + w * 64) * 8),
          16, 0, 0);
    }
  };

  auto LDA = [&](int d, int mi, int ks) -> short8 {
    const int row = wm * 64 + mi * 16 + lrow;       // 0..127
    const int ch  = (c0 | (ks << 2)) ^ sx;
    return *(const short8*)&lds[d * 8192 + row * 64 + ch * 8];
  };
  auto LDB = [&](int d, int ni, int ks) -> short8 {
    const int row = wn * 48 + ni * 16 + lrow;       // 0..191
    const int ch  = (c0 | (ks << 2)) ^ sx;
    return *(const short8*)&lds[16384 + d * 12288 + row * 64 + ch * 8];
  };

  // ---- prologue: A(0),A(1) reg-staged+written; B(0),B(1) DMA'd; regs(2) ----
  ISSUE(0);
  asm volatile("s_waitcnt vmcnt(0)" ::: "memory");
  CVTW(0);
  ISSUE(1);
  BDMA(0, 0);
  BDMA(1, 1);
  asm volatile("s_waitcnt vmcnt(6)" ::: "memory");   // ISSUE(1)'s 8 done
  CVTW(1);
  ISSUE(2);
  asm volatile("s_waitcnt vmcnt(0) lgkmcnt(0)" ::: "memory");
  BAR();

  for (int tau = 0; tau < NKT; ++tau) {
    const int d = tau & 1;
    short8 bf[3];
    __builtin_amdgcn_s_setprio(1);
#pragma unroll
    for (int ni = 0; ni < 3; ++ni) bf[ni] = LDB(d, ni, 0);
#pragma unroll
    for (int mi = 0; mi < 4; ++mi) {
      const short8 af = LDA(d, mi, 0);
#pragma unroll
      for (int ni = 0; ni < 3; ++ni)
        acc[mi][ni] = __builtin_amdgcn_mfma_f32_16x16x32_bf16(af, bf[ni], acc[mi][ni], 0, 0, 0);
    }
#pragma unroll
    for (int ni = 0; ni < 3; ++ni) bf[ni] = LDB(d, ni, 1);
#pragma unroll
    for (int mi = 0; mi < 4; ++mi) {
      const short8 af = LDA(d, mi, 1);
#pragma unroll
      for (int ni = 0; ni < 3; ++ni)
        acc[mi][ni] = __builtin_amdgcn_mfma_f32_16x16x32_bf16(af, bf[ni], acc[mi][ni], 0, 0, 0);
    }
    __builtin_amdgcn_s_setprio(0);
    // all dbuf-d reads done (mine: lgkm; all waves: BAR); in-flight regs +
    // B-DMA for this slot drained (vmcnt 0 — newest load is a full tile old)
    asm volatile("s_waitcnt vmcnt(0) lgkmcnt(0)" ::: "memory");
    BAR();
    if (tau + 2 < NKT) { CVTW(d); BDMA(d, tau + 2); }  // stage τ+2 -> dbuf d
    if (tau + 3 < NKT) ISSUE(tau + 3);                 // refill regs
    __builtin_amdgcn_sched_barrier(0);
  }
  asm volatile("s_waitcnt vmcnt(0)" ::: "memory");

  // C-write: rhs[(bk*1024 + it*128 + row)][nt*192 + col] bf16
  unsigned short* Cw = rhs + ((size_t)bk * Nn + it * BM) * TF + nt * BN;
#pragma unroll
  for (int mi = 0; mi < 4; ++mi) {
#pragma unroll
    for (int ni = 0; ni < 3; ++ni) {
      const int col = wn * 48 + ni * 16 + lrow;
      const int row0 = wm * 64 + mi * 16 + c0 * 4;
      unsigned short* op = Cw + (size_t)row0 * TF + col;
      f32x4 v = acc[mi][ni];
#pragma unroll
      for (int q = 0; q < 4; ++q)
        op[(size_t)q * TF] = f2bf(v[q]);
    }
  }
}

// ---------------------------------------------------------------------------
// k4: out[b,t,i,o] = relu( sum_{k,f} rhs[b,k,i,t*32+f] * Theta[k,f,o] )
// (UNCHANGED)
// ---------------------------------------------------------------------------
__global__ __launch_bounds__(256) void k4_epilogue(
    const unsigned short* __restrict__ rhs, const float* __restrict__ theta,
    float* __restrict__ out) {
  __shared__ float th[KC * FIN * FOUT];  // 24 KB, [kf][o]
  const int tid = threadIdx.x;
  for (int s = tid; s < KC * FIN * FOUT; s += 256) th[s] = theta[s];
  __syncthreads();
  const int bid = blockIdx.x;            // (b*12 + t)*4 + ic
  const int ic = bid & 3;
  const int bt = bid >> 2;
  const int t = bt % Tt, b = bt / Tt;
  const int w = tid >> 6, l = tid & 63;
  const int lrow = l & 15;
  const int c0 = l >> 4;
  const int i0 = ic * 256 + w * 64;

  short8 bfrag[KC][4];
#pragma unroll
  for (int ks = 0; ks < KC; ++ks)
#pragma unroll
    for (int oi = 0; oi < 4; ++oi) {
      short8 bf;
#pragma unroll
      for (int rr = 0; rr < 8; ++rr)
        bf[rr] = (short)f2bf(th[(ks * FIN + c0 * 8 + rr) * FOUT + oi * 16 + lrow]);
      bfrag[ks][oi] = bf;
    }

  f32x4 acc[4][4];
#pragma unroll
  for (int mi = 0; mi < 4; ++mi)
#pragma unroll
    for (int oi = 0; oi < 4; ++oi)
      acc[mi][oi] = (f32x4){0.f, 0.f, 0.f, 0.f};

#pragma unroll
  for (int ks = 0; ks < KC; ++ks) {
#pragma unroll
    for (int mi = 0; mi < 4; ++mi) {
      const short8 af = *(const short8*)(
          rhs + ((size_t)(b * KC + ks) * Nn + i0 + mi * 16 + lrow) * TF + t * FIN + c0 * 8);
#pragma unroll
      for (int oi = 0; oi < 4; ++oi)
        acc[mi][oi] = __builtin_amdgcn_mfma_f32_16x16x32_bf16(af, bfrag[ks][oi], acc[mi][oi], 0, 0, 0);
    }
  }

#pragma unroll
  for (int mi = 0; mi < 4; ++mi) {
#pragma unroll
    for (int oi = 0; oi < 4; ++oi) {
      const int row = i0 + mi * 16 + c0 * 4;
      float* op = out + ((size_t)(b * Tt + t) * Nn + row) * FOUT + oi * 16 + lrow;
      f32x4 v = acc[mi][oi];
#pragma unroll
      for (int q = 0; q < 4; ++q)
        op[(size_t)q * FOUT] = fmaxf(v[q], 0.f);
    }
  }
}

// ---------------------------------------------------------------------------
// fallback (ws too small): slow but correct, pure f32
// ---------------------------------------------------------------------------
__global__ __launch_bounds__(128) void k_fallback(
    const float* __restrict__ x, const float* __restrict__ att,
    const float* __restrict__ cheb, const float* __restrict__ theta,
    float* __restrict__ out) {
  const int blk = blockIdx.x;  // (b, t, i)
  const int i = blk & 1023;
  const int bt = blk >> 10;
  const int t = bt % Tt, b = bt / Tt;
  __shared__ float rhs[KC * FIN];
  const int tid = threadIdx.x;
  if (tid < KC * FIN) {
    const int k = tid >> 5, f = tid & 31;
    const float* ar = att + ((size_t)b * Nn + i) * Nn;
    const float* cr = cheb + ((size_t)k * Nn + i) * Nn;
    const float* xr = x + ((size_t)(b * Tt + t) * Nn) * FIN + f;
    float s = 0.f;
    for (int j = 0; j < Nn; ++j) s = fmaf(ar[j] * cr[j], xr[(size_t)j * FIN], s);
    rhs[tid] = s;
  }
  __syncthreads();
  if (tid < FOUT) {
    float a = 0.f;
#pragma unroll
    for (int kf = 0; kf < KC * FIN; ++kf) a = fmaf(rhs[kf], theta[kf * FOUT + tid], a);
    out[((size_t)(b * Tt + t) * Nn + i) * FOUT + tid] = fmaxf(a, 0.f);
  }
}

extern "C" void kernel_launch(void* const* d_in, const int* in_sizes, int n_in,
                              void* d_out, int out_size, void* d_ws, size_t ws_size,
                              hipStream_t stream) {
  const float* x     = (const float*)d_in[0];
  const float* att   = (const float*)d_in[1];
  const float* cheb  = (const float*)d_in[2];
  const float* theta = (const float*)d_in[3];
  float* out = (float*)d_out;

  const size_t needYx = (size_t)Bb * TF * Nn * sizeof(unsigned short);      // 12.6 MB
  const size_t needR  = (size_t)Bb * KC * Nn * TF * sizeof(unsigned short); // 37.7 MB
  if (ws_size >= needYx + needR) {
    unsigned short* YxT = (unsigned short*)d_ws;
    unsigned short* rhs = (unsigned short*)((char*)d_ws + needYx);
    hipLaunchKernelGGL(k2r_build_YxT, dim3(Bb * Tt * 4), dim3(256), 0, stream,
                       x, YxT);
    hipLaunchKernelGGL(k3f_gemm, dim3(48 * (Nn / BM) * (TF / BN)), dim3(512), 0, stream,
                       att, cheb, YxT, rhs);
    hipLaunchKernelGGL(k4_epilogue, dim3(Bb * Tt * 4), dim3(256), 0, stream,
                       rhs, theta, out);
  } else {
    hipLaunchKernelGGL(k_fallback, dim3(Bb * Tt * Nn), dim3(128), 0, stream,
                       x, att, cheb, theta, out);
  }
}